// Round 3
// baseline (440.578 us; speedup 1.0000x reference)
//
#include <hip/hip_runtime.h>

// ResNet theta-step, elementwise closed iteration + scalar fmin reduction.
// x: (4096, 16384) fp32. out: same shape fp32, then one extra float = fmin.
//
// Per element (H=1, THETA=0.5, MAXNITER=10):
//   e   = x + 0.5*relu(x)
//   z0  = e;  z_{k+1} = e + 0.5*relu(z_k)   (10 iterations)
//   out = e + 0.5*relu(z10)
//   r   = z10 - e - 0.5*relu(z10)
//   fmin = 0.5 * sum(r^2)
//
// Memory-bound: 256 MiB in + 256 MiB out, floor ~85 us @ 6.29 TB/s copy
// ceiling (m13, plain float4 copy). History:
//   R0 naive grid-stride:            kernel ~105 us (total 437.3)
//   R1 +1-deep pipeline +nt:         kernel  ~98 us (total 428.7)  <- best
//   R2 2-wide pipeline +nt:          kernel ~102 us (total 432.8)  MLP ruled out
// R3 (this): decompose R1's bundle — keep the 1-deep pipeline, DROP all
// nontemporal hints (m13's 6.29 TB/s reference copy uses plain cached
// accesses; nt no-allocate policy may defeat TCC write-combining for streams).

#define THETA 0.5f
#define ONE_MINUS_THETA 0.5f
#define NITER 10

typedef float v4f __attribute__((ext_vector_type(4)));

__device__ __forceinline__ float process_one(float xv, float& acc) {
    float e = xv + ONE_MINUS_THETA * fmaxf(xv, 0.0f);   // H = 1
    float z = e;
#pragma unroll
    for (int it = 0; it < NITER; ++it) {
        z = e + THETA * fmaxf(z, 0.0f);
    }
    float rz = THETA * fmaxf(z, 0.0f);
    float o  = e + rz;
    float r  = z - e - rz;
    acc += 0.5f * r * r;
    return o;
}

__global__ __launch_bounds__(256) void resnet_step_kernel(
    const float* __restrict__ x, float* __restrict__ out,
    float* __restrict__ fmin_out, int n4)
{
    const v4f* __restrict__ x4 = (const v4f*)x;
    v4f* __restrict__ o4 = (v4f*)out;

    float local = 0.0f;
    const int stride = gridDim.x * blockDim.x;
    int i = blockIdx.x * blockDim.x + threadIdx.x;

    if (i < n4) {
        // software pipeline: keep one load in flight across the compute chain
        v4f v = x4[i];
        int cur = i;
        int nxt = i + stride;
        for (;;) {
            const bool more = (nxt < n4);
            v4f vn;
            if (more) vn = x4[nxt];  // issue next-iteration load early

            v4f o;
            o.x = process_one(v.x, local);
            o.y = process_one(v.y, local);
            o.z = process_one(v.z, local);
            o.w = process_one(v.w, local);
            o4[cur] = o;

            if (!more) break;
            v = vn;
            cur = nxt;
            nxt += stride;
        }
    }

    // wave-64 shuffle reduction
#pragma unroll
    for (int off = 32; off > 0; off >>= 1) {
        local += __shfl_down(local, off, 64);
    }

    __shared__ float s_partial[4];  // 256 threads = 4 waves
    const int lane = threadIdx.x & 63;
    const int wid  = threadIdx.x >> 6;
    if (lane == 0) s_partial[wid] = local;
    __syncthreads();
    if (threadIdx.x == 0) {
        float t = s_partial[0] + s_partial[1] + s_partial[2] + s_partial[3];
        atomicAdd(fmin_out, t);  // device-scope by default on CDNA
    }
}

extern "C" void kernel_launch(void* const* d_in, const int* in_sizes, int n_in,
                              void* d_out, int out_size, void* d_ws, size_t ws_size,
                              hipStream_t stream) {
    const float* x = (const float*)d_in[0];
    float* out = (float*)d_out;
    const int n = in_sizes[0];          // 4096*16384 = 67108864 (divisible by 4)
    float* fmin_out = out + n;          // out_size = n + 1

    // d_out is re-poisoned to 0xAA before every timed replay — zero the
    // accumulator slot ourselves (async memset is graph-capture legal).
    hipMemsetAsync(fmin_out, 0, sizeof(float), stream);

    const int n4 = n / 4;
    dim3 block(256);
    dim3 grid(2048);                    // 8 blocks/CU * 256 CUs = 32 waves/CU
    resnet_step_kernel<<<grid, block, 0, stream>>>(x, out, fmin_out, n4);
}

// Round 4
// 427.685 us; speedup vs baseline: 1.0301x; 1.0301x over previous
//
#include <hip/hip_runtime.h>

// ResNet theta-step, elementwise closed iteration + scalar fmin reduction.
// x: (4096, 16384) fp32. out: same shape fp32, then one extra float = fmin.
//
// Per element (H=1, THETA=0.5, MAXNITER=10):
//   e   = x + 0.5*relu(x)
//   z0  = e;  z_{k+1} = e + 0.5*relu(z_k)   (10 iterations)
//   out = e + 0.5*relu(z10)
//   r   = z10 - e - 0.5*relu(z10)
//   fmin = 0.5 * sum(r^2)
//
// Memory-bound. Decomposition ledger (kernel time inferred = dur_us - 2 fills):
//   R0 naive grid-stride:           kernel ~105 us (total 437.3)
//   R1 1-deep pipeline + nt:        kernel  ~98 us (total 428.7)  <- BEST
//   R2 2-wide pipeline + nt:        kernel ~102 us (total 432.8)  MLP: ruled out
//   R3 1-deep pipeline, cached:     kernel ~116 us (total 440.6)  nt worth -18us
// Floor: 2 fills (~330us, harness-fixed) + 536.9MB @ 6.29 TB/s copy ceiling
// (~85us) + memset/launch (~3us) ~= 418us. R1 is within ~2.6% of floor.
// This round: exact revert to R1 (reproduce best before declaring roofline).

#define THETA 0.5f
#define ONE_MINUS_THETA 0.5f
#define NITER 10

typedef float v4f __attribute__((ext_vector_type(4)));

__device__ __forceinline__ float process_one(float xv, float& acc) {
    float e = xv + ONE_MINUS_THETA * fmaxf(xv, 0.0f);   // H = 1
    float z = e;
#pragma unroll
    for (int it = 0; it < NITER; ++it) {
        z = e + THETA * fmaxf(z, 0.0f);
    }
    float rz = THETA * fmaxf(z, 0.0f);
    float o  = e + rz;
    float r  = z - e - rz;
    acc += 0.5f * r * r;
    return o;
}

__global__ __launch_bounds__(256) void resnet_step_kernel(
    const float* __restrict__ x, float* __restrict__ out,
    float* __restrict__ fmin_out, int n4)
{
    const v4f* __restrict__ x4 = (const v4f*)x;
    v4f* __restrict__ o4 = (v4f*)out;

    float local = 0.0f;
    const int stride = gridDim.x * blockDim.x;
    int i = blockIdx.x * blockDim.x + threadIdx.x;

    if (i < n4) {
        // software pipeline: keep one load in flight across the compute chain
        v4f v = __builtin_nontemporal_load(&x4[i]);
        int cur = i;
        int nxt = i + stride;
        for (;;) {
            const bool more = (nxt < n4);
            v4f vn;
            if (more) vn = __builtin_nontemporal_load(&x4[nxt]);  // issue early

            v4f o;
            o.x = process_one(v.x, local);
            o.y = process_one(v.y, local);
            o.z = process_one(v.z, local);
            o.w = process_one(v.w, local);
            __builtin_nontemporal_store(o, &o4[cur]);

            if (!more) break;
            v = vn;
            cur = nxt;
            nxt += stride;
        }
    }

    // wave-64 shuffle reduction
#pragma unroll
    for (int off = 32; off > 0; off >>= 1) {
        local += __shfl_down(local, off, 64);
    }

    __shared__ float s_partial[4];  // 256 threads = 4 waves
    const int lane = threadIdx.x & 63;
    const int wid  = threadIdx.x >> 6;
    if (lane == 0) s_partial[wid] = local;
    __syncthreads();
    if (threadIdx.x == 0) {
        float t = s_partial[0] + s_partial[1] + s_partial[2] + s_partial[3];
        atomicAdd(fmin_out, t);  // device-scope by default on CDNA
    }
}

extern "C" void kernel_launch(void* const* d_in, const int* in_sizes, int n_in,
                              void* d_out, int out_size, void* d_ws, size_t ws_size,
                              hipStream_t stream) {
    const float* x = (const float*)d_in[0];
    float* out = (float*)d_out;
    const int n = in_sizes[0];          // 4096*16384 = 67108864 (divisible by 4)
    float* fmin_out = out + n;          // out_size = n + 1

    // d_out is re-poisoned to 0xAA before every timed replay — zero the
    // accumulator slot ourselves (async memset is graph-capture legal).
    hipMemsetAsync(fmin_out, 0, sizeof(float), stream);

    const int n4 = n / 4;
    dim3 block(256);
    dim3 grid(2048);                    // 8 blocks/CU * 256 CUs = 32 waves/CU
    resnet_step_kernel<<<grid, block, 0, stream>>>(x, out, fmin_out, n4);
}